// Round 8
// baseline (420.046 us; speedup 1.0000x reference)
//
#include <hip/hip_runtime.h>
#include <hip/hip_bf16.h>
#include <stdint.h>

// ---------------------------------------------------------------------------
// AttentionBlock: y = Attn(RoPE(x@wq^T), RoPE(x@wk^T), x@wv^T) @ wo^T
// B=2 T=2048 D=2048 H=32 HD=64. FP32 in/out, bf16 MFMA internal.
//
// r10 -> r11 post-mortem: r10 (triple-buffer 4-phase) = 150.2us, MfmaUtil
// 28.8%, conflicts 0. Stall isolated by arithmetic: 8 MFMA/wave/phase =
// 77cy matrix work per SIMD vs ~120cy unoverlappable barrier+ds-latency
// per phase -> 39% ceiling. Also ks-innermost MFMA order made dependent
// back-to-back pairs on the same acc.
// r11 (minimal change, same indices/layout/swizzle/ledger):
//  - merge 4 phases -> 2 per K-tile: 16 MFMA/wave/phase (308cy/SIMD vs
//    ~120cy overhead -> ~60% ceiling, m201-like), 4 barriers/K-tile.
//  - MFMA loops ks-OUTERMOST: dependency distance 8 (was 1).
//  - staging 3 sweeps/phase; vmcnt(6) once per K-tile (ledger unchanged:
//    12 outstanding after prologue, oscillates 9->12->6).
// flash v5 / casts / wo-gemm byte-identical to r10.
// ---------------------------------------------------------------------------

typedef __bf16 bf16_t;
typedef __bf16 bf16x4 __attribute__((ext_vector_type(4)));
typedef __bf16 bf16x8 __attribute__((ext_vector_type(8)));
typedef float  f32x4  __attribute__((ext_vector_type(4)));

constexpr int B_ = 2, T_ = 2048, D_ = 2048, H_ = 32, HD_ = 64;
constexpr int M_ = B_ * T_;   // 4096 token rows

// async global->LDS, 16B per lane; LDS dest = wave-uniform base + lane*16
__device__ __forceinline__ void async_copy16(const bf16_t* g, bf16_t* l) {
  __builtin_amdgcn_global_load_lds(
      (const __attribute__((address_space(1))) void*)g,
      (__attribute__((address_space(3))) void*)l, 16, 0, 0);
}

#define GQ_BAR()   __builtin_amdgcn_s_barrier()
#define GQ_FENCE() asm volatile("" ::: "memory")

// ---------------------------------------------------------------------------
// f32 -> bf16 cast, 4 elements/thread (single-tensor; used for wo + Path B).
// ---------------------------------------------------------------------------
__global__ __launch_bounds__(256) void cast_f32_bf16(
    const float* __restrict__ src, bf16_t* __restrict__ dst, int n4)
{
  const int i = blockIdx.x * 256 + threadIdx.x;
  if (i >= n4) return;
  const float4 v = ((const float4*)src)[i];
  bf16x4 o;
  o[0] = (bf16_t)v.x; o[1] = (bf16_t)v.y; o[2] = (bf16_t)v.z; o[3] = (bf16_t)v.w;
  ((bf16x4*)dst)[i] = o;
}

// ---------------------------------------------------------------------------
// Merged cast: x -> xb, wq|wk|wv -> wb3 (one dispatch instead of four).
// ---------------------------------------------------------------------------
__global__ __launch_bounds__(256) void cast_qkvx(
    const float* __restrict__ x, const float* __restrict__ wq,
    const float* __restrict__ wk, const float* __restrict__ wv,
    bf16_t* __restrict__ xb, bf16_t* __restrict__ wb3, int nx4, int nw4)
{
  const int i = blockIdx.x * 256 + threadIdx.x;
  const int total = nx4 + 3 * nw4;
  if (i >= total) return;
  const float* src; bf16_t* dst; int idx;
  if (i < nx4) { src = x; dst = xb; idx = i; }
  else {
    const int j = i - nx4;
    const int wsel = j / nw4;
    idx = j - wsel * nw4;
    src = (wsel == 0) ? wq : (wsel == 1) ? wk : wv;
    dst = wb3 + (size_t)wsel * (size_t)nw4 * 4;
  }
  const float4 v = ((const float4*)src)[idx];
  bf16x4 o;
  o[0] = (bf16_t)v.x; o[1] = (bf16_t)v.y; o[2] = (bf16_t)v.z; o[3] = (bf16_t)v.w;
  ((bf16x4*)dst)[idx] = o;
}

// ---------------------------------------------------------------------------
// GEMM: C[M][N] = A[M][K] . B[N][K]^T — m97 structure (wo-gemm + Path B).
// ---------------------------------------------------------------------------
template <typename OutT>
__global__ __launch_bounds__(256, 2) void gemm_bt(
    const bf16_t* __restrict__ A, const bf16_t* __restrict__ B,
    OutT* __restrict__ C, int M, int N, int K)
{
  __shared__ __attribute__((aligned(16))) bf16_t As[128 * 32];
  __shared__ __attribute__((aligned(16))) bf16_t Bs[128 * 32];

  const int tid    = threadIdx.x;
  const int w      = tid >> 6;
  const int l      = tid & 63;
  const int quad   = l >> 4;
  const int lane16 = l & 15;
  const int bm0 = blockIdx.x * 128;
  const int bn0 = blockIdx.y * 128;
  const int wm  = (w >> 1) * 64;
  const int wn  = (w & 1) * 64;
  const int srow = l >> 2;
  const int scol = (l & 3) * 8;

  const bf16_t* Ag = A + (size_t)bm0 * K;
  const bf16_t* Bg = B + (size_t)bn0 * K;

  f32x4 acc[4][4] = {};

  for (int kk = 0; kk < K; kk += 32) {
    __syncthreads();
#pragma unroll
    for (int s0 = 0; s0 < 2; ++s0) {
      const int s = w + s0 * 4;
      async_copy16(Ag + (size_t)(s * 16 + srow) * K + kk + scol, &As[s * 512]);
      async_copy16(Bg + (size_t)(s * 16 + srow) * K + kk + scol, &Bs[s * 512]);
    }
    __syncthreads();

    bf16x8 af[4], bfr[4];
#pragma unroll
    for (int i = 0; i < 4; ++i)
      af[i] = *(const bf16x8*)&As[(wm + i * 16 + lane16) * 32 + quad * 8];
#pragma unroll
    for (int j = 0; j < 4; ++j)
      bfr[j] = *(const bf16x8*)&Bs[(wn + j * 16 + lane16) * 32 + quad * 8];
#pragma unroll
    for (int i = 0; i < 4; ++i)
#pragma unroll
      for (int j = 0; j < 4; ++j)
        acc[i][j] = __builtin_amdgcn_mfma_f32_16x16x32_bf16(af[i], bfr[j],
                                                            acc[i][j], 0, 0, 0);
  }

#pragma unroll
  for (int i = 0; i < 4; ++i) {
#pragma unroll
    for (int r = 0; r < 4; ++r) {
      const size_t row = (size_t)(bm0 + wm + i * 16 + quad * 4 + r);
#pragma unroll
      for (int j = 0; j < 4; ++j) {
        const int col = bn0 + wn + j * 16 + lane16;
        C[row * N + col] = (OutT)acc[i][j][r];
      }
    }
  }
}

// ---------------------------------------------------------------------------
// Merged-QKV GEMM v3: 128x256 tile, BK=64, 512 threads (8 waves, 2M x 4N),
// triple-buffered counted-vmcnt pipeline, T2 LDS swizzle, fused RoPE.
// 2 phases per K-tile, 16 MFMA/wave/phase, ks-outermost.
// A[4096][2048], Bw = concat(wq|wk|wv) [6144][2048]. Grid: 768 blocks.
// Per buffer: A tile 128x64 (16KB, elems +0) | B tile 256x64 (32KB, +8192).
// Chunk16 layout: logical (row, c16) stored at chunk (row, c16 ^ (row&7)).
// ---------------------------------------------------------------------------
__global__ __launch_bounds__(512, 1) void gemm_qkv8(
    const bf16_t* __restrict__ A, const bf16_t* __restrict__ Bw,
    bf16_t* __restrict__ Cq, bf16_t* __restrict__ Ck, bf16_t* __restrict__ Cv,
    const float* __restrict__ fc, const float* __restrict__ fs)
{
  __shared__ __attribute__((aligned(16))) bf16_t lds[3 * 24576];  // 144 KiB
  constexpr int K = 2048;
  constexpr int NT = 32;               // K-tiles

  const int tid    = threadIdx.x;
  const int w      = tid >> 6;
  const int l      = tid & 63;
  const int quad   = l >> 4;
  const int lane16 = l & 15;
  const int wm = (w >> 2) * 64;        // 0,64
  const int wn = (w & 3) * 64;         // 0..192

  // T1: XCD-chunked bijective swizzle (768 % 8 == 0). lin sweeps bm fastest.
  const int lin = (blockIdx.x & 7) * 96 + (blockIdx.x >> 3);
  const int bm0 = (lin & 31) << 7;     // *128
  const int bn0 = (lin >> 5) << 8;     // *256

  // staging: thread -> (row-in-sweep = tid>>3, chunk16 = tid&7), 16B each.
  // inverse swizzle on the GLOBAL column; LDS dest linear.
  const int rsel = (tid >> 3) & 7;
  const size_t soff = (size_t)(tid >> 3) * K + (((tid & 7) ^ rsel) << 3);

  const bf16_t* Ag = A  + (size_t)bm0 * K;
  const bf16_t* Bg = Bw + (size_t)bn0 * K;

  // sweep = 64 rows x 64 cols = 8KB = 4096 elems. ebase = buf elem base.
  auto stS = [&](const bf16_t* gb, int s, int kt, int ebase) {
    async_copy16(gb + (size_t)(s * 64) * K + kt * 64 + soff,
                 &lds[ebase + s * 4096 + w * 512]);
  };
  // per K-tile: B sweeps 0..3 (ebase+8192), A sweeps 0..1 (ebase+0)

  // fragment-read swizzled chunk offsets (bytes): row&7 == lane16&7 always.
  const int r7  = lane16 & 7;
  const int sw0 = ((0 + quad) ^ r7) << 4;     // ks=0
  const int sw1 = ((4 + quad) ^ r7) << 4;     // ks=1
  const char* ldsc = (const char*)lds;

  f32x4 acc[4][4] = {};

  // prologue: tile 0 -> buf0, tile 1 -> buf1
#pragma unroll
  for (int s = 0; s < 4; ++s) stS(Bg, s, 0, 0 * 24576 + 8192);
#pragma unroll
  for (int s = 0; s < 2; ++s) stS(Ag, s, 0, 0 * 24576);
#pragma unroll
  for (int s = 0; s < 4; ++s) stS(Bg, s, 1, 1 * 24576 + 8192);
#pragma unroll
  for (int s = 0; s < 2; ++s) stS(Ag, s, 1, 1 * 24576);
  asm volatile("s_waitcnt vmcnt(6)" ::: "memory");   // tile 0 landed
  GQ_BAR();
  GQ_FENCE();

  int cur = 0, stg = 2;
#pragma unroll 1
  for (int t = 0; t < NT; ++t) {
    const int ktn = (t + 2 < NT) ? t + 2 : NT - 1;   // addr clamp (tail)
    const int cb = cur * 49152;                       // byte base, compute buf
    const int sA = stg * 24576;                       // elem base, stage buf
    const int sB = sA + 8192;

    bf16x8 a[4][2], b0[2][2], b1[2][2];

    // ---- ph0: read A i0-3 + B j0-1 (12 ds_reads) | stage B sweeps 0-2 ----
#pragma unroll
    for (int i = 0; i < 4; ++i) {
      const int ra = (wm + i * 16 + lane16) * 128;
      a[i][0] = *(const bf16x8*)(ldsc + cb + ra + sw0);
      a[i][1] = *(const bf16x8*)(ldsc + cb + ra + sw1);
    }
#pragma unroll
    for (int j = 0; j < 2; ++j) {
      const int rb = (wn + j * 16 + lane16) * 128;
      b0[j][0] = *(const bf16x8*)(ldsc + cb + 16384 + rb + sw0);
      b0[j][1] = *(const bf16x8*)(ldsc + cb + 16384 + rb + sw1);
    }
    stS(Bg, 0, ktn, sB); stS(Bg, 1, ktn, sB); stS(Bg, 2, ktn, sB);
    GQ_BAR(); GQ_FENCE();
    __builtin_amdgcn_s_setprio(1);
#pragma unroll
    for (int ks = 0; ks < 2; ++ks)        // ks OUTER: dep distance 8
#pragma unroll
      for (int i = 0; i < 4; ++i)
#pragma unroll
        for (int j = 0; j < 2; ++j)
          acc[i][j] = __builtin_amdgcn_mfma_f32_16x16x32_bf16(
              a[i][ks], b0[j][ks], acc[i][j], 0, 0, 0);
    __builtin_amdgcn_s_setprio(0);
    GQ_BAR(); GQ_FENCE();

    // ---- ph1: read B j2-3 (4 ds_reads) | stage B sweep 3 + A sweeps 0-1 ----
#pragma unroll
    for (int j = 0; j < 2; ++j) {
      const int rb = (wn + 32 + j * 16 + lane16) * 128;
      b1[j][0] = *(const bf16x8*)(ldsc + cb + 16384 + rb + sw0);
      b1[j][1] = *(const bf16x8*)(ldsc + cb + 16384 + rb + sw1);
    }
    stS(Bg, 3, ktn, sB); stS(Ag, 0, ktn, sA); stS(Ag, 1, ktn, sA);
    GQ_BAR(); GQ_FENCE();
    __builtin_amdgcn_s_setprio(1);
#pragma unroll
    for (int ks = 0; ks < 2; ++ks)        // ks OUTER
#pragma unroll
      for (int i = 0; i < 4; ++i)
#pragma unroll
        for (int j = 0; j < 2; ++j)
          acc[i][2 + j] = __builtin_amdgcn_mfma_f32_16x16x32_bf16(
              a[i][ks], b1[j][ks], acc[i][2 + j], 0, 0, 0);
    __builtin_amdgcn_s_setprio(0);
    asm volatile("s_waitcnt vmcnt(6)" ::: "memory");   // tile t+1 landed
    GQ_BAR(); GQ_FENCE();

    cur = (cur == 2) ? 0 : cur + 1;
    stg = (stg == 2) ? 0 : stg + 1;
  }

  asm volatile("s_waitcnt vmcnt(0)" ::: "memory");   // drain clamped tails

  // ---- epilogue: base select + fused RoPE (q scaled by 1/sqrt(HD)) ----
  bf16_t* Cb; float qs; int dorope;
  if (bn0 < 2048)      { Cb = Cq; qs = 0.125f; dorope = 1; }
  else if (bn0 < 4096) { Cb = Ck; qs = 1.0f;   dorope = 1; }
  else                 { Cb = Cv; qs = 1.0f;   dorope = 0; }
  const int cb0 = (bn0 & 2047) + wn;
#pragma unroll
  for (int i = 0; i < 4; ++i) {
#pragma unroll
    for (int r = 0; r < 4; ++r) {
      const size_t row = (size_t)(bm0 + wm + i * 16 + quad * 4 + r);
      const int t = (int)(row & (T_ - 1));
#pragma unroll
      for (int j = 0; j < 4; ++j) {
        float v = acc[i][j][r];
        if (dorope) {                      // block-uniform branch
          const int hd = j * 16 + lane16;  // dim within head
          const float c  = fc[t * 32 + (hd >> 1)];
          const float s  = fs[t * 32 + (hd >> 1)];
          const float pr = __shfl_xor(v, 1);    // pair partner (col ^ 1)
          v = ((hd & 1) ? (pr * s + v * c) : (v * c - pr * s)) * qs;
        }
        Cb[row * 2048 + cb0 + j * 16 + lane16] = (bf16_t)v;
      }
    }
  }
}

// ---------------------------------------------------------------------------
// RoPE in-place on bf16 q,k; folds 1/sqrt(64)=0.125 into q. (Path B only.)
// ---------------------------------------------------------------------------
__global__ __launch_bounds__(256) void rope_kernel(
    bf16_t* __restrict__ q, bf16_t* __restrict__ k,
    const float* __restrict__ cosb, const float* __restrict__ sinb, int npair)
{
  const int idx = blockIdx.x * 256 + threadIdx.x;
  if (idx >= npair) return;
  const int p = idx & 31;
  const int t = (idx >> 10) & (T_ - 1);
  const float c = cosb[t * 32 + p];
  const float s = sinb[t * 32 + p];
  const size_t off = (size_t)idx * 2;

  const float qr = (float)q[off], qi = (float)q[off + 1];
  q[off]     = (bf16_t)((qr * c - qi * s) * 0.125f);
  q[off + 1] = (bf16_t)((qr * s + qi * c) * 0.125f);

  const float kr = (float)k[off], ki = (float)k[off + 1];
  k[off]     = (bf16_t)(kr * c - ki * s);
  k[off + 1] = (bf16_t)(kr * s + ki * c);
}

// ---------------------------------------------------------------------------
// Flash attention v5 (causal, fixed-bias softmax, PAIRED q-groups).
// Verbatim from r9/r10 (measured-correct).
// ---------------------------------------------------------------------------
__global__ __launch_bounds__(256, 2) void flash_attn(
    const bf16_t* __restrict__ Q, const bf16_t* __restrict__ K,
    const bf16_t* __restrict__ V, bf16_t* __restrict__ Y)
{
  __shared__ __attribute__((aligned(16))) bf16_t Vf[4096];
  __shared__ __attribute__((aligned(16))) bf16_t Pt[4 * 2 * 16 * 68];

  const int tid    = threadIdx.x;
  const int w      = tid >> 6;
  const int l      = tid & 63;
  const int quad   = l >> 4;
  const int lane16 = l & 15;
  const int bh = blockIdx.y;
  const int b  = bh >> 5;
  const int h  = bh & 31;
  const int gx = blockIdx.x;            // 0..7
  int qa[2];
  qa[0] = gx * 128 + w * 32;            // light group
  qa[1] = (15 - gx) * 128 + w * 32;     // heavy group
  const size_t rs = (size_t)H_ * HD_;

  const bf16_t* Qb = Q + ((size_t)b * T_) * rs + h * HD_;
  const bf16_t* Kb = K + ((size_t)b * T_) * rs + h * HD_;
  const bf16_t* Vb = V + ((size_t)b * T_) * rs + h * HD_;

  // Q B-frags: [grp][tile][chunk]  n=lane16(q-row), k=quad*8+j(dim)
  bf16x8 qf[2][2][2];
#pragma unroll
  for (int g = 0; g < 2; ++g)
#pragma unroll
    for (int t = 0; t < 2; ++t)
#pragma unroll
      for (int c = 0; c < 2; ++c)
        qf[g][t][c] = *(const bf16x8*)(Qb + (size_t)(qa[g] + t * 16 + lane16) * rs +
                                       c * 32 + quad * 8);

  f32x4 o[2][2][4] = {};       // [grp][tile][dim-tile]
  float lsum[2][2] = {};       // [grp][tile]

  // V staging assignment: thread = (key-offset, dim-octet)
  const int koff = tid >> 3;
  const int oct  = tid & 7;
  const int d0   = oct * 8;
  const int nV = oct >> 1, base16 = (oct & 1) * 8;

  bf16_t* const PtW = Pt + w * (2 * 16 * 68);

  const int nsteps = (15 - gx) * 2 + 2;   // keys [0, (15-gx)*128 + 128)

  // prefetch V step 0
  bf16x8 vr[2];
#pragma unroll
  for (int hf = 0; hf < 2; ++hf)
    vr[hf] = *(const bf16x8*)(Vb + (size_t)(hf * 32 + koff) * rs + d0);

  for (int it = 0; it < nsteps; ++it) {
    const int k0 = it * 64;
    __syncthreads();                     // WAR: prev-step Vf reads done
#pragma unroll
    for (int hf = 0; hf < 2; ++hf) {
      const int key = hf * 32 + koff;
      const int cV = key >> 5, qV = (key >> 3) & 3, jV = key & 7;
#pragma unroll
      for (int i = 0; i < 8; ++i) {
        const int gv = ((cV * 4 + nV) * 16 + base16 + i) * 4 + qV;
        Vf[(gv ^ oct) * 8 + jV] = vr[hf][i];
      }
    }
    __syncthreads();                     // Vf visible
    if (it + 1 < nsteps) {
      const int k0n = k0 + 64;
#pragma unroll
      for (int hf = 0; hf < 2; ++hf)
        vr[hf] = *(const bf16x8*)(Vb + (size_t)(k0n + hf * 32 + koff) * rs + d0);
    }

    // K tile A-frags straight from global (L1/L2-resident; both groups share)
    bf16x8 kf2[2][4];
#pragma unroll
    for (int c = 0; c < 2; ++c)
#pragma unroll
      for (int kt = 0; kt < 4; ++kt)
        kf2[c][kt] = *(const bf16x8*)(Kb + (size_t)(k0 + kt * 16 + lane16) * rs +
                                      c * 32 + quad * 8);

#pragma unroll
    for (int g = 0; g < 2; ++g) {
      if (k0 > qa[g] + 31) continue;     // group fully masked (wave-uniform)

      // ---- S^T = K.Q^T ----
      f32x4 stx[4][2] = {};
#pragma unroll
      for (int c = 0; c < 2; ++c) {
#pragma unroll
        for (int kt = 0; kt < 4; ++kt) {
          stx[kt][0] = __builtin_amdgcn_mfma_f32_16x16x32_bf16(kf2[c][kt], qf[g][0][c],
                                                               stx[kt][0], 0, 0, 0);
          stx[kt][1] = __builtin_amdgcn_mfma_f32_16x16x32_bf16(kf2[c][kt], qf[g][1][c],
                                                               stx[kt][1], 0, 0, 0);
        }
      }

      // ---- softmax numerator (no max; s bounded ~|q||k|/8) ----
#pragma unroll
      for (int t = 0; t < 2; ++t) {
        const int qbase = qa[g] + t * 16;
#pragma unroll
        for (int kt = 0; kt < 4; ++kt) {
          const int kbase = k0 + kt * 16 + quad * 4;
          const bool anymask = (k0 + kt * 16 + 15) > qbase;   // wave-uniform
          float p[4];
#pragma unroll
          for (int r = 0; r < 4; ++r) {
            float s = stx[kt][t][r];
            if (anymask) s = (kbase + r > qbase + lane16) ? -1e30f : s;
            p[r] = __expf(s);
          }
          lsum[g][t] += (p[0] + p[1]) + (p[2] + p[3]);
          bf16x4 pv;
          pv[0] = (bf16_t)p[0]; pv[1] = (bf16_t)p[1];
          pv[2] = (bf16_t)p[2]; pv[3] = (bf16_t)p[3];
          *(bf16x4*)&PtW[(t * 16 + lane16) * 68 + kt * 16 + quad * 4] = pv;
        }
      }

      // ---- O += P.V ----
#pragma unroll
      for (int c = 0; c < 2; ++c) {
        const bf16x8 pf0 = *(const bf16x8*)&PtW[(0 * 16 + lane16) * 68 + c * 32 + quad * 8];
        const bf16x8 pf1 = *(const bf16x8*)&PtW[(1 * 16 + lane16) * 68 + c * 32 + quad * 8];
#pragma unroll
        for (int n = 0; n < 4; ++n) {
          const int gv = ((c * 4 + n) * 16 + lane16) * 4 + quad;
          const int swz = n * 2 + (lane16 >> 3);
          const bf16x8 vfr = *(const bf16x8*)&Vf[(gv ^ swz) * 8];
          o[g][0][n] = __builtin_amdgcn_mfma_f32_16x16x32_bf16(pf0, vfr, o[g][0][n], 0, 0, 0);
          o[g][1][n] = __builtin_amdgcn_mfma_f32_16x16x32_bf16(pf1, vfr, o[g][1][n], 0, 0, 0);
        }
      }
    }
  }

  // ---- epilogue ----
  bf16_t* Yb = Y + ((size_t)b * T_) * rs + h * HD_;
#pragma unroll
  for (int g = 0; g < 2; ++g) {
#pragma unroll
    for (int t = 0; t < 2; ++t) {
      float lt = lsum[g][t];
      lt += __shfl_xor(lt, 16);
      lt += __shfl_xor(lt, 32);
#pragma unroll
      for (int r = 0; r < 4; ++r) {
        const float linv = 1.0f / __shfl(lt, quad * 4 + r);
        const size_t row = (size_t)(qa[g] + t * 16 + quad * 4 + r);
#pragma unroll
        for (int n = 0; n < 4; ++n)
          Yb[row * rs + n * 16 + lane16] = (bf16_t)(o[g][t][n][r] * linv);
      }
    }
  }
}

// ---------------------------------------------------------------------------
extern "C" void kernel_launch(void* const* d_in, const int* in_sizes, int n_in,
                              void* d_out, int out_size, void* d_ws, size_t ws_size,
                              hipStream_t stream)
{
  (void)in_sizes; (void)n_in; (void)out_size;
  const float* x  = (const float*)d_in[0];
  const float* fc = (const float*)d_in[1];
  const float* fs = (const float*)d_in[2];
  const float* wq = (const float*)d_in[3];
  const float* wk = (const float*)d_in[4];
  const float* wv = (const float*)d_in[5];
  const float* wo = (const float*)d_in[6];
  float* out = (float*)d_out;

  const size_t nx = (size_t)M_ * D_;        // 8.39M
  const size_t nw = (size_t)D_ * D_;        // 4.19M
  const dim3 blk(256);
  const int nx4 = (int)(nx / 4), nw4 = (int)(nw / 4);
  const dim3 gg(M_ / 128, D_ / 128);        // 32 x 16

  if (ws_size >= (3 * nw + 4 * nx) * sizeof(bf16_t)) {
    // ---- Path A: triple-buffered QKV gemm + fused RoPE (92.3 MB ws) ----
    // layout: wb3[3*nw] | xb[nx] | qb[nx] | kb[nx] | vb[nx]; yb aliases xb.
    bf16_t* ws  = (bf16_t*)d_ws;
    bf16_t* wb3 = ws;
    bf16_t* xb  = ws + 3 * nw;
    bf16_t* qb  = xb + nx;
    bf16_t* kb  = qb + nx;
    bf16_t* vb  = kb + nx;
    bf16_t* yb  = xb;

    const int ntot4 = nx4 + 3 * nw4;
    cast_qkvx<<<dim3(ntot4 / 256), blk, 0, stream>>>(x, wq, wk, wv, xb, wb3,
                                                     nx4, nw4);

    gemm_qkv8<<<dim3(768), dim3(512), 0, stream>>>(xb, wb3, qb, kb, vb, fc, fs);

    flash_attn<<<dim3(8, B_ * H_), blk, 0, stream>>>(qb, kb, vb, yb);

    cast_f32_bf16<<<dim3(nw4 / 256), blk, 0, stream>>>(wo, wb3, nw4);
    gemm_bt<float><<<gg, blk, 0, stream>>>(yb, wb3, out, M_, D_, D_);
  } else {
    // ---- Path B: serial 3-gemm (75.5 MB ws) ----
    bf16_t* ws = (bf16_t*)d_ws;
    bf16_t* wb = ws;
    bf16_t* xb = ws + nw;
    bf16_t* qb = xb + nx;
    bf16_t* kb = qb + nx;
    bf16_t* vb = kb + nx;
    bf16_t* yb = xb;

    cast_f32_bf16<<<dim3(nx4 / 256), blk, 0, stream>>>(x, xb, nx4);
    cast_f32_bf16<<<dim3(nw4 / 256), blk, 0, stream>>>(wq, wb, nw4);
    gemm_bt<bf16_t><<<gg, blk, 0, stream>>>(xb, wb, qb, M_, D_, D_);
    cast_f32_bf16<<<dim3(nw4 / 256), blk, 0, stream>>>(wk, wb, nw4);
    gemm_bt<bf16_t><<<gg, blk, 0, stream>>>(xb, wb, kb, M_, D_, D_);
    cast_f32_bf16<<<dim3(nw4 / 256), blk, 0, stream>>>(wv, wb, nw4);
    gemm_bt<bf16_t><<<gg, blk, 0, stream>>>(xb, wb, vb, M_, D_, D_);

    rope_kernel<<<dim3((B_ * T_ * H_ * 32) / 256), blk, 0, stream>>>(
        qb, kb, fc, fs, B_ * T_ * H_ * 32);
    flash_attn<<<dim3(8, B_ * H_), blk, 0, stream>>>(qb, kb, vb, yb);

    cast_f32_bf16<<<dim3(nw4 / 256), blk, 0, stream>>>(wo, wb, nw4);
    gemm_bt<float><<<gg, blk, 0, stream>>>(yb, wb, out, M_, D_, D_);
  }
}

// Round 10
// 414.154 us; speedup vs baseline: 1.0142x; 1.0142x over previous
//
#include <hip/hip_runtime.h>
#include <hip/hip_bf16.h>
#include <stdint.h>

// ---------------------------------------------------------------------------
// AttentionBlock: y = Attn(RoPE(x@wq^T), RoPE(x@wk^T), x@wv^T) @ wo^T
// B=2 T=2048 D=2048 H=32 HD=64. FP32 in/out, bf16 MFMA internal.
//
// r12 -> r13: fix compile error only — __exp2f is not a HIP device function
// (CUDA spelling); use exp2f() which lowers to v_exp_f32. All r12 content
// unchanged:
//  (1) flash softmax exp -> exp2: log2(e) folded into the gemm's fused
//      RoPE q-scale (qs = 0.125*1.442695); exp2f = bare v_exp_f32.
//  (2) 5-tensor cast merge (x,wq,wk,wv,wo in ONE dispatch) when ws_size
//      allows an extra nw slot -> deletes the mid-stream wo-cast kernel
//      and its launch gap. Runtime-guarded; falls back to r6 path.
// flash = r6's measured version (K via LDS). gemm_qkv = r6 (m97 + fused
// RoPE, 146.5us measured). GEMM restructuring remains STOPPED (r5/r10/r11
// all converged to the m97 ceiling).
// ---------------------------------------------------------------------------

typedef __bf16 bf16_t;
typedef __bf16 bf16x4 __attribute__((ext_vector_type(4)));
typedef __bf16 bf16x8 __attribute__((ext_vector_type(8)));
typedef float  f32x4  __attribute__((ext_vector_type(4)));

constexpr int B_ = 2, T_ = 2048, D_ = 2048, H_ = 32, HD_ = 64;
constexpr int M_ = B_ * T_;   // 4096 token rows

// 0.125 (1/sqrt(HD)) * log2(e): q pre-scale so softmax can use exp2.
#define QSCALE_EXP2 0.18033688011f

// async global->LDS, 16B per lane; LDS dest = wave-uniform base + lane*16
__device__ __forceinline__ void async_copy16(const bf16_t* g, bf16_t* l) {
  __builtin_amdgcn_global_load_lds(
      (const __attribute__((address_space(1))) void*)g,
      (__attribute__((address_space(3))) void*)l, 16, 0, 0);
}

// ---------------------------------------------------------------------------
// f32 -> bf16 cast, 4 elements/thread (single-tensor; wo + Path B).
// ---------------------------------------------------------------------------
__global__ __launch_bounds__(256) void cast_f32_bf16(
    const float* __restrict__ src, bf16_t* __restrict__ dst, int n4)
{
  const int i = blockIdx.x * 256 + threadIdx.x;
  if (i >= n4) return;
  const float4 v = ((const float4*)src)[i];
  bf16x4 o;
  o[0] = (bf16_t)v.x; o[1] = (bf16_t)v.y; o[2] = (bf16_t)v.z; o[3] = (bf16_t)v.w;
  ((bf16x4*)dst)[i] = o;
}

// ---------------------------------------------------------------------------
// Merged cast (4 tensors): x -> xb, wq|wk|wv -> wb3.
// ---------------------------------------------------------------------------
__global__ __launch_bounds__(256) void cast_qkvx(
    const float* __restrict__ x, const float* __restrict__ wq,
    const float* __restrict__ wk, const float* __restrict__ wv,
    bf16_t* __restrict__ xb, bf16_t* __restrict__ wb3, int nx4, int nw4)
{
  const int i = blockIdx.x * 256 + threadIdx.x;
  const int total = nx4 + 3 * nw4;
  if (i >= total) return;
  const float* src; bf16_t* dst; int idx;
  if (i < nx4) { src = x; dst = xb; idx = i; }
  else {
    const int j = i - nx4;
    const int wsel = j / nw4;
    idx = j - wsel * nw4;
    src = (wsel == 0) ? wq : (wsel == 1) ? wk : wv;
    dst = wb3 + (size_t)wsel * (size_t)nw4 * 4;
  }
  const float4 v = ((const float4*)src)[idx];
  bf16x4 o;
  o[0] = (bf16_t)v.x; o[1] = (bf16_t)v.y; o[2] = (bf16_t)v.z; o[3] = (bf16_t)v.w;
  ((bf16x4*)dst)[idx] = o;
}

// ---------------------------------------------------------------------------
// Merged cast (5 tensors): x -> xb, wq|wk|wv -> wb3, wo -> wob.
// One leading dispatch; removes the mid-stream wo cast + its launch gap.
// ---------------------------------------------------------------------------
__global__ __launch_bounds__(256) void cast_qkvxo(
    const float* __restrict__ x, const float* __restrict__ wq,
    const float* __restrict__ wk, const float* __restrict__ wv,
    const float* __restrict__ wo,
    bf16_t* __restrict__ xb, bf16_t* __restrict__ wb3,
    bf16_t* __restrict__ wob, int nx4, int nw4)
{
  const int i = blockIdx.x * 256 + threadIdx.x;
  const int total = nx4 + 4 * nw4;
  if (i >= total) return;
  const float* src; bf16_t* dst; int idx;
  if (i < nx4) { src = x; dst = xb; idx = i; }
  else {
    const int j = i - nx4;
    const int wsel = j / nw4;                 // 0..3
    idx = j - wsel * nw4;
    src = (wsel == 0) ? wq : (wsel == 1) ? wk : (wsel == 2) ? wv : wo;
    dst = (wsel == 3) ? wob : wb3 + (size_t)wsel * (size_t)nw4 * 4;
  }
  const float4 v = ((const float4*)src)[idx];
  bf16x4 o;
  o[0] = (bf16_t)v.x; o[1] = (bf16_t)v.y; o[2] = (bf16_t)v.z; o[3] = (bf16_t)v.w;
  ((bf16x4*)dst)[idx] = o;
}

// ---------------------------------------------------------------------------
// GEMM: C[M][N] = A[M][K] . B[N][K]^T — m97 structure (wo-gemm + Path B).
// ---------------------------------------------------------------------------
template <typename OutT>
__global__ __launch_bounds__(256, 2) void gemm_bt(
    const bf16_t* __restrict__ A, const bf16_t* __restrict__ B,
    OutT* __restrict__ C, int M, int N, int K)
{
  __shared__ __attribute__((aligned(16))) bf16_t As[128 * 32];
  __shared__ __attribute__((aligned(16))) bf16_t Bs[128 * 32];

  const int tid    = threadIdx.x;
  const int w      = tid >> 6;
  const int l      = tid & 63;
  const int quad   = l >> 4;
  const int lane16 = l & 15;
  const int bm0 = blockIdx.x * 128;
  const int bn0 = blockIdx.y * 128;
  const int wm  = (w >> 1) * 64;
  const int wn  = (w & 1) * 64;
  const int srow = l >> 2;
  const int scol = (l & 3) * 8;

  const bf16_t* Ag = A + (size_t)bm0 * K;
  const bf16_t* Bg = B + (size_t)bn0 * K;

  f32x4 acc[4][4] = {};

  for (int kk = 0; kk < K; kk += 32) {
    __syncthreads();
#pragma unroll
    for (int s0 = 0; s0 < 2; ++s0) {
      const int s = w + s0 * 4;
      async_copy16(Ag + (size_t)(s * 16 + srow) * K + kk + scol, &As[s * 512]);
      async_copy16(Bg + (size_t)(s * 16 + srow) * K + kk + scol, &Bs[s * 512]);
    }
    __syncthreads();

    bf16x8 af[4], bfr[4];
#pragma unroll
    for (int i = 0; i < 4; ++i)
      af[i] = *(const bf16x8*)&As[(wm + i * 16 + lane16) * 32 + quad * 8];
#pragma unroll
    for (int j = 0; j < 4; ++j)
      bfr[j] = *(const bf16x8*)&Bs[(wn + j * 16 + lane16) * 32 + quad * 8];
#pragma unroll
    for (int i = 0; i < 4; ++i)
#pragma unroll
      for (int j = 0; j < 4; ++j)
        acc[i][j] = __builtin_amdgcn_mfma_f32_16x16x32_bf16(af[i], bfr[j],
                                                            acc[i][j], 0, 0, 0);
  }

#pragma unroll
  for (int i = 0; i < 4; ++i) {
#pragma unroll
    for (int r = 0; r < 4; ++r) {
      const size_t row = (size_t)(bm0 + wm + i * 16 + quad * 4 + r);
#pragma unroll
      for (int j = 0; j < 4; ++j) {
        const int col = bn0 + wn + j * 16 + lane16;
        C[row * N + col] = (OutT)acc[i][j][r];
      }
    }
  }
}

// ---------------------------------------------------------------------------
// Merged-QKV GEMM (m97 structure, 146.5us measured) + fused RoPE epilogue.
// B = concat(wq|wk|wv) [6144][2048]; epilogue base-selects into compact
// q/k/v buffers and applies RoPE; q scaled by 0.125*log2(e) (exp2 softmax).
// ---------------------------------------------------------------------------
__global__ __launch_bounds__(256, 2) void gemm_qkv(
    const bf16_t* __restrict__ A, const bf16_t* __restrict__ B,
    bf16_t* __restrict__ Cq, bf16_t* __restrict__ Ck, bf16_t* __restrict__ Cv,
    const float* __restrict__ fc, const float* __restrict__ fs,
    int M, int K)
{
  __shared__ __attribute__((aligned(16))) bf16_t As[128 * 32];
  __shared__ __attribute__((aligned(16))) bf16_t Bs[128 * 32];

  const int tid    = threadIdx.x;
  const int w      = tid >> 6;
  const int l      = tid & 63;
  const int quad   = l >> 4;
  const int lane16 = l & 15;
  const int bm0 = blockIdx.x * 128;
  const int bn0 = blockIdx.y * 128;
  const int wm  = (w >> 1) * 64;
  const int wn  = (w & 1) * 64;
  const int srow = l >> 2;
  const int scol = (l & 3) * 8;

  const bf16_t* Ag = A + (size_t)bm0 * K;
  const bf16_t* Bg = B + (size_t)bn0 * K;

  f32x4 acc[4][4] = {};

  for (int kk = 0; kk < K; kk += 32) {
    __syncthreads();
#pragma unroll
    for (int s0 = 0; s0 < 2; ++s0) {
      const int s = w + s0 * 4;
      async_copy16(Ag + (size_t)(s * 16 + srow) * K + kk + scol, &As[s * 512]);
      async_copy16(Bg + (size_t)(s * 16 + srow) * K + kk + scol, &Bs[s * 512]);
    }
    __syncthreads();

    bf16x8 af[4], bfr[4];
#pragma unroll
    for (int i = 0; i < 4; ++i)
      af[i] = *(const bf16x8*)&As[(wm + i * 16 + lane16) * 32 + quad * 8];
#pragma unroll
    for (int j = 0; j < 4; ++j)
      bfr[j] = *(const bf16x8*)&Bs[(wn + j * 16 + lane16) * 32 + quad * 8];
#pragma unroll
    for (int i = 0; i < 4; ++i)
#pragma unroll
      for (int j = 0; j < 4; ++j)
        acc[i][j] = __builtin_amdgcn_mfma_f32_16x16x32_bf16(af[i], bfr[j],
                                                            acc[i][j], 0, 0, 0);
  }

  // ---- epilogue: base select + fused RoPE ----
  // q scale = 1/sqrt(HD) * log2(e) so flash can use exp2 (exact transform).
  bf16_t* Cb; float qs; int dorope;
  if (bn0 < 2048)      { Cb = Cq; qs = QSCALE_EXP2; dorope = 1; }
  else if (bn0 < 4096) { Cb = Ck; qs = 1.0f;        dorope = 1; }
  else                 { Cb = Cv; qs = 1.0f;        dorope = 0; }
  const int cb0 = (bn0 & 2047) + wn;
#pragma unroll
  for (int i = 0; i < 4; ++i) {
#pragma unroll
    for (int r = 0; r < 4; ++r) {
      const size_t row = (size_t)(bm0 + wm + i * 16 + quad * 4 + r);
      const int t = (int)(row & (T_ - 1));
#pragma unroll
      for (int j = 0; j < 4; ++j) {
        float v = acc[i][j][r];
        if (dorope) {                      // block-uniform branch
          const int hd = j * 16 + lane16;  // dim within head
          const float c  = fc[t * 32 + (hd >> 1)];
          const float s  = fs[t * 32 + (hd >> 1)];
          const float pr = __shfl_xor(v, 1);    // pair partner (col ^ 1)
          v = ((hd & 1) ? (pr * s + v * c) : (v * c - pr * s)) * qs;
        }
        Cb[row * 2048 + cb0 + j * 16 + lane16] = (bf16_t)v;
      }
    }
  }
}

// ---------------------------------------------------------------------------
// RoPE in-place on bf16 q,k; q scaled 0.125*log2(e) (exp2 flash). Path B.
// ---------------------------------------------------------------------------
__global__ __launch_bounds__(256) void rope_kernel(
    bf16_t* __restrict__ q, bf16_t* __restrict__ k,
    const float* __restrict__ cosb, const float* __restrict__ sinb, int npair)
{
  const int idx = blockIdx.x * 256 + threadIdx.x;
  if (idx >= npair) return;
  const int p = idx & 31;
  const int t = (idx >> 10) & (T_ - 1);
  const float c = cosb[t * 32 + p];
  const float s = sinb[t * 32 + p];
  const size_t off = (size_t)idx * 2;

  const float qr = (float)q[off], qi = (float)q[off + 1];
  q[off]     = (bf16_t)((qr * c - qi * s) * QSCALE_EXP2);
  q[off + 1] = (bf16_t)((qr * s + qi * c) * QSCALE_EXP2);

  const float kr = (float)k[off], ki = (float)k[off + 1];
  k[off]     = (bf16_t)(kr * c - ki * s);
  k[off + 1] = (bf16_t)(kr * s + ki * c);
}

// ---------------------------------------------------------------------------
// Flash attention (r6's measured-correct v3: K+V staged in LDS, fragment-
// granule K, XOR-swizzled transposed V, padded per-wave P) with ONE change:
// __expf -> exp2f (q pre-scaled by log2(e) upstream).
// Block gx handles q-groups {gx*128, (15-gx)*128}; 4 waves x 32 rows/group.
// ---------------------------------------------------------------------------
__global__ __launch_bounds__(256, 2) void flash_attn(
    const bf16_t* __restrict__ Q, const bf16_t* __restrict__ K,
    const bf16_t* __restrict__ V, bf16_t* __restrict__ Y)
{
  __shared__ __attribute__((aligned(16))) bf16_t Kf[4096];
  __shared__ __attribute__((aligned(16))) bf16_t Vf[4096];
  __shared__ __attribute__((aligned(16))) bf16_t Pt[4 * 2 * 16 * 68];

  const int tid    = threadIdx.x;
  const int w      = tid >> 6;
  const int l      = tid & 63;
  const int quad   = l >> 4;
  const int lane16 = l & 15;
  const int bh = blockIdx.y;
  const int b  = bh >> 5;
  const int h  = bh & 31;
  const int gx = blockIdx.x;            // 0..7
  int qa[2];
  qa[0] = gx * 128 + w * 32;            // light group
  qa[1] = (15 - gx) * 128 + w * 32;     // heavy group
  const size_t rs = (size_t)H_ * HD_;

  const bf16_t* Qb = Q + ((size_t)b * T_) * rs + h * HD_;
  const bf16_t* Kb = K + ((size_t)b * T_) * rs + h * HD_;
  const bf16_t* Vb = V + ((size_t)b * T_) * rs + h * HD_;

  // Q B-frags: [grp][tile][chunk]  n=lane16(q-row), k=quad*8+j(dim)
  bf16x8 qf[2][2][2];
#pragma unroll
  for (int g = 0; g < 2; ++g)
#pragma unroll
    for (int t = 0; t < 2; ++t)
#pragma unroll
      for (int c = 0; c < 2; ++c)
        qf[g][t][c] = *(const bf16x8*)(Qb + (size_t)(qa[g] + t * 16 + lane16) * rs +
                                       c * 32 + quad * 8);

  f32x4 o[2][2][4] = {};       // [grp][tile][dim-tile]
  float lsum[2][2] = {};       // [grp][tile]

  // staging assignment: thread = (key-offset, dim-octet)
  const int koff = tid >> 3;
  const int oct  = tid & 7;
  const int d0   = oct * 8;
  const int kc = oct >> 2, kq = oct & 3;
  const int nV = oct >> 1, base16 = (oct & 1) * 8;

  bf16_t* const PtW = Pt + w * (2 * 16 * 68);

  const int nsteps = (15 - gx) * 2 + 2;   // keys [0, (15-gx)*128 + 128)

  // prefetch step 0
  bf16x8 kr[2], vr[2];
#pragma unroll
  for (int hf = 0; hf < 2; ++hf) {
    const int key = hf * 32 + koff;
    kr[hf] = *(const bf16x8*)(Kb + (size_t)key * rs + d0);
    vr[hf] = *(const bf16x8*)(Vb + (size_t)key * rs + d0);
  }

  for (int it = 0; it < nsteps; ++it) {
    const int k0 = it * 64;
    __syncthreads();
#pragma unroll
    for (int hf = 0; hf < 2; ++hf) {
      const int key = hf * 32 + koff;
      const int gK = ((kc * 4 + (key >> 4)) * 16 + (key & 15)) * 4 + kq;
      *(bf16x8*)&Kf[gK * 8] = kr[hf];
      const int cV = key >> 5, qV = (key >> 3) & 3, jV = key & 7;
#pragma unroll
      for (int i = 0; i < 8; ++i) {
        const int gv = ((cV * 4 + nV) * 16 + base16 + i) * 4 + qV;
        Vf[(gv ^ oct) * 8 + jV] = vr[hf][i];
      }
    }
    __syncthreads();
    if (it + 1 < nsteps) {
      const int k0n = k0 + 64;
#pragma unroll
      for (int hf = 0; hf < 2; ++hf) {
        const int key = k0n + hf * 32 + koff;
        kr[hf] = *(const bf16x8*)(Kb + (size_t)key * rs + d0);
        vr[hf] = *(const bf16x8*)(Vb + (size_t)key * rs + d0);
      }
    }

#pragma unroll
    for (int g = 0; g < 2; ++g) {
      if (k0 > qa[g] + 31) continue;       // group fully masked (wave-uniform)

      // ---- S^T = K.Q^T ----
      f32x4 stx[4][2] = {};
#pragma unroll
      for (int c = 0; c < 2; ++c) {
#pragma unroll
        for (int kt = 0; kt < 4; ++kt) {
          const bf16x8 kfr =
              *(const bf16x8*)&Kf[(((c * 4 + kt) * 16 + lane16) * 4 + quad) * 8];
          stx[kt][0] = __builtin_amdgcn_mfma_f32_16x16x32_bf16(kfr, qf[g][0][c],
                                                               stx[kt][0], 0, 0, 0);
          stx[kt][1] = __builtin_amdgcn_mfma_f32_16x16x32_bf16(kfr, qf[g][1][c],
                                                               stx[kt][1], 0, 0, 0);
        }
      }

      // ---- softmax numerator: exp2 (q pre-scaled by log2(e)/8) ----
#pragma unroll
      for (int t = 0; t < 2; ++t) {
        const int qbase = qa[g] + t * 16;
#pragma unroll
        for (int kt = 0; kt < 4; ++kt) {
          const int kbase = k0 + kt * 16 + quad * 4;
          const bool anymask = (k0 + kt * 16 + 15) > qbase;   // wave-uniform
          float p[4];
#pragma unroll
          for (int r = 0; r < 4; ++r) {
            float s = stx[kt][t][r];
            if (anymask) s = (kbase + r > qbase + lane16) ? -1e30f : s;
            p[r] = exp2f(s);
          }
          lsum[g][t] += (p[0] + p[1]) + (p[2] + p[3]);
          bf16x4 pv;
          pv[0] = (bf16_t)p[0]; pv[1] = (bf16_t)p[1];
          pv[2] = (bf16_t)p[2]; pv[3] = (bf16_t)p[3];
          *(bf16x4*)&PtW[(t * 16 + lane16) * 68 + kt * 16 + quad * 4] = pv;
        }
      }

      // ---- O += P.V ----
#pragma unroll
      for (int c = 0; c < 2; ++c) {
        const bf16x8 pf0 = *(const bf16x8*)&PtW[(0 * 16 + lane16) * 68 + c * 32 + quad * 8];
        const bf16x8 pf1 = *(const bf16x8*)&PtW[(1 * 16 + lane16) * 68 + c * 32 + quad * 8];
#pragma unroll
        for (int n = 0; n < 4; ++n) {
          const int gv = ((c * 4 + n) * 16 + lane16) * 4 + quad;
          const int swz = n * 2 + (lane16 >> 3);
          const bf16x8 vfr = *(const bf16x8*)&Vf[(gv ^ swz) * 8];
          o[g][0][n] = __builtin_amdgcn_mfma_f32_16x16x32_bf16(pf0, vfr, o[g][0][n], 0, 0, 0);
          o[g][1][n] = __builtin_amdgcn_mfma_f32_16x16x32_bf16(pf1, vfr, o[g][1][n], 0, 0, 0);
        }
      }
    }
  }

  // ---- epilogue ----
  bf16_t* Yb = Y + ((size_t)b * T_) * rs + h * HD_;
#pragma unroll
  for (int g = 0; g < 2; ++g) {
#pragma unroll
    for (int t = 0; t < 2; ++t) {
      float lt = lsum[g][t];
      lt += __shfl_xor(lt, 16);
      lt += __shfl_xor(lt, 32);
#pragma unroll
      for (int r = 0; r < 4; ++r) {
        const float linv = 1.0f / __shfl(lt, quad * 4 + r);
        const size_t row = (size_t)(qa[g] + t * 16 + quad * 4 + r);
#pragma unroll
        for (int n = 0; n < 4; ++n)
          Yb[row * rs + n * 16 + lane16] = (bf16_t)(o[g][t][n][r] * linv);
      }
    }
  }
}

// ---------------------------------------------------------------------------
extern "C" void kernel_launch(void* const* d_in, const int* in_sizes, int n_in,
                              void* d_out, int out_size, void* d_ws, size_t ws_size,
                              hipStream_t stream)
{
  (void)in_sizes; (void)n_in; (void)out_size;
  const float* x  = (const float*)d_in[0];
  const float* fc = (const float*)d_in[1];
  const float* fs = (const float*)d_in[2];
  const float* wq = (const float*)d_in[3];
  const float* wk = (const float*)d_in[4];
  const float* wv = (const float*)d_in[5];
  const float* wo = (const float*)d_in[6];
  float* out = (float*)d_out;

  const size_t nx = (size_t)M_ * D_;        // 8.39M
  const size_t nw = (size_t)D_ * D_;        // 4.19M
  const dim3 blk(256);
  const int nx4 = (int)(nx / 4), nw4 = (int)(nw / 4);
  const dim3 gg(M_ / 128, D_ / 128);        // 32 x 16

  if (ws_size >= (3 * nw + 4 * nx) * sizeof(bf16_t)) {
    // ---- Path A: merged QKV gemm + fused RoPE ----
    // layout: wb3[3nw] | xb[nx] | qb[nx] | kb[nx] | vb[nx] | (wob[nw] if fits)
    bf16_t* ws  = (bf16_t*)d_ws;
    bf16_t* wb3 = ws;
    bf16_t* xb  = ws + 3 * nw;
    bf16_t* qb  = xb + nx;
    bf16_t* kb  = qb + nx;
    bf16_t* vb  = kb + nx;
    bf16_t* yb  = xb;
    bf16_t* wob = vb + nx;

    const bool bigws = ws_size >= (4 * nw + 4 * nx) * sizeof(bf16_t);

    if (bigws) {
      const int ntot4 = nx4 + 4 * nw4;       // 24576 blocks exact
      cast_qkvxo<<<dim3(ntot4 / 256), blk, 0, stream>>>(
          x, wq, wk, wv, wo, xb, wb3, wob, nx4, nw4);
    } else {
      const int ntot4 = nx4 + 3 * nw4;
      cast_qkvx<<<dim3(ntot4 / 256), blk, 0, stream>>>(x, wq, wk, wv, xb, wb3,
                                                       nx4, nw4);
    }

    gemm_qkv<<<dim3(M_ / 128, 48), blk, 0, stream>>>(xb, wb3, qb, kb, vb,
                                                     fc, fs, M_, D_);

    flash_attn<<<dim3(8, B_ * H_), blk, 0, stream>>>(qb, kb, vb, yb);

    const bf16_t* wg;
    if (bigws) {
      wg = wob;
    } else {
      cast_f32_bf16<<<dim3(nw4 / 256), blk, 0, stream>>>(wo, wb3, nw4);
      wg = wb3;
    }
    gemm_bt<float><<<gg, blk, 0, stream>>>(yb, wg, out, M_, D_, D_);
  } else {
    // ---- Path B: serial 3-gemm (75.5 MB ws) ----
    bf16_t* ws = (bf16_t*)d_ws;
    bf16_t* wb = ws;
    bf16_t* xb = ws + nw;
    bf16_t* qb = xb + nx;
    bf16_t* kb = qb + nx;
    bf16_t* vb = kb + nx;
    bf16_t* yb = xb;

    cast_f32_bf16<<<dim3(nx4 / 256), blk, 0, stream>>>(x, xb, nx4);
    cast_f32_bf16<<<dim3(nw4 / 256), blk, 0, stream>>>(wq, wb, nw4);
    gemm_bt<bf16_t><<<gg, blk, 0, stream>>>(xb, wb, qb, M_, D_, D_);
    cast_f32_bf16<<<dim3(nw4 / 256), blk, 0, stream>>>(wk, wb, nw4);
    gemm_bt<bf16_t><<<gg, blk, 0, stream>>>(xb, wb, kb, M_, D_, D_);
    cast_f32_bf16<<<dim3(nw4 / 256), blk, 0, stream>>>(wv, wb, nw4);
    gemm_bt<bf16_t><<<gg, blk, 0, stream>>>(xb, wb, vb, M_, D_, D_);

    rope_kernel<<<dim3((B_ * T_ * H_ * 32) / 256), blk, 0, stream>>>(
        qb, kb, fc, fs, B_ * T_ * H_ * 32);
    flash_attn<<<dim3(8, B_ * H_), blk, 0, stream>>>(qb, kb, vb, yb);

    cast_f32_bf16<<<dim3(nw4 / 256), blk, 0, stream>>>(wo, wb, nw4);
    gemm_bt<float><<<gg, blk, 0, stream>>>(yb, wb, out, M_, D_, D_);
  }
}